// Round 1
// baseline (28.230 us; speedup 1.0000x reference)
//
#include <hip/hip_runtime.h>

#define LN_EPS 1e-5f
#define D 256
#define V 256

// Kernel 1: build per-token-id logits table T[V][D_out=V].
// One block per token id v, 256 threads (one per channel / output logit).
__global__ __launch_bounds__(256) void build_table(
    const float* __restrict__ embed,   // [V, D]
    const float* __restrict__ filt,    // [D]
    const float* __restrict__ lnw,     // [D]
    const float* __restrict__ lnb,     // [D]
    const float* __restrict__ Wout,    // [V, D]
    const float* __restrict__ bout,    // [V]
    float* __restrict__ T)             // [V, V]
{
    const int v = blockIdx.x;
    const int t = threadIdx.x;

    __shared__ float hn[D];
    __shared__ float red[8];

    // FFT mixing + residual == scale by (1 + filter[d])
    float e = embed[v * D + t] * (1.0f + filt[t]);

    // block reduction for mean / var (4 waves of 64)
    float s = e, sq = e * e;
    #pragma unroll
    for (int off = 32; off > 0; off >>= 1) {
        s  += __shfl_down(s, off, 64);
        sq += __shfl_down(sq, off, 64);
    }
    const int wave = t >> 6;
    const int lane = t & 63;
    if (lane == 0) { red[wave * 2] = s; red[wave * 2 + 1] = sq; }
    __syncthreads();
    const float ts = red[0] + red[2] + red[4] + red[6];
    const float tq = red[1] + red[3] + red[5] + red[7];
    const float mu  = ts * (1.0f / D);
    const float var = tq * (1.0f / D) - mu * mu;
    const float inv = rsqrtf(var + LN_EPS);

    hn[t] = (e - mu) * inv * lnw[t] + lnb[t];
    __syncthreads();

    // output logit u = t : dot(hn, Wout[u,:]) + bout[u]
    float acc = bout[t];
    const float* w = Wout + t * D;
    #pragma unroll 8
    for (int d = 0; d < D; ++d)
        acc += hn[d] * w[d];
    T[v * V + t] = acc;
}

// Kernel 2: out[token_idx, :] = T[x[token_idx], :], vectorized as float4.
// 64 consecutive float4 = one token row, so each aligned wave handles exactly
// one token (wave-uniform x load, fully coalesced T read + out write).
__global__ __launch_bounds__(256) void gather_logits(
    const int* __restrict__ x,        // [B*L] token ids
    const float4* __restrict__ T4,    // [V * (V/4)]
    float4* __restrict__ out4,        // [B*L * (V/4)]
    int total4)
{
    int i = blockIdx.x * blockDim.x + threadIdx.x;
    const int stride = gridDim.x * blockDim.x;
    for (; i < total4; i += stride) {
        const int tok = x[i >> 6];                 // V/4 = 64 float4 per row
        out4[i] = T4[(tok << 6) | (i & 63)];
    }
}

extern "C" void kernel_launch(void* const* d_in, const int* in_sizes, int n_in,
                              void* d_out, int out_size, void* d_ws, size_t ws_size,
                              hipStream_t stream) {
    const int*   x     = (const int*)  d_in[0];   // [B*L] = 65536
    const float* embed = (const float*)d_in[1];   // [256,256]
    const float* filt  = (const float*)d_in[2];   // [256]
    const float* lnw   = (const float*)d_in[3];
    const float* lnb   = (const float*)d_in[4];
    const float* Wout  = (const float*)d_in[5];   // [256,256]
    const float* bout  = (const float*)d_in[6];   // [256]
    float* out = (float*)d_out;

    float* T = (float*)d_ws;                      // 256*256*4 = 256 KB scratch

    build_table<<<V, 256, 0, stream>>>(embed, filt, lnw, lnb, Wout, bout, T);

    const int n_tok  = in_sizes[0];               // 65536
    const int total4 = n_tok * (V / 4);           // 4,194,304 float4
    gather_logits<<<2048, 256, 0, stream>>>(x, (const float4*)T, (float4*)out, total4);
}

// Round 3
// 25.557 us; speedup vs baseline: 1.1046x; 1.1046x over previous
//
#include <hip/hip_runtime.h>

#define LN_EPS 1e-5f
#define D 256
#define V 256

typedef float fv4 __attribute__((ext_vector_type(4)));

// Kernel 1: build per-token-id logits table T[V][V].
// One block per token id v, 256 threads (one per output logit).
__global__ __launch_bounds__(256) void build_table(
    const float* __restrict__ embed,   // [V, D]
    const float* __restrict__ filt,    // [D]
    const float* __restrict__ lnw,     // [D]
    const float* __restrict__ lnb,     // [D]
    const float* __restrict__ Wout,    // [V, D]
    const float* __restrict__ bout,    // [V]
    float* __restrict__ T)             // [V, V]
{
    const int v = blockIdx.x;
    const int t = threadIdx.x;

    __shared__ fv4 hn4[D / 4];
    __shared__ float red[8];

    // FFT mixing + residual == scale channel d by (1 + filter[d])
    float e = embed[v * D + t] * (1.0f + filt[t]);

    // block reduction for mean / var (4 waves of 64)
    float s = e, sq = e * e;
    #pragma unroll
    for (int off = 32; off > 0; off >>= 1) {
        s  += __shfl_down(s, off, 64);
        sq += __shfl_down(sq, off, 64);
    }
    const int wave = t >> 6;
    const int lane = t & 63;
    if (lane == 0) { red[wave * 2] = s; red[wave * 2 + 1] = sq; }
    __syncthreads();
    const float ts = red[0] + red[2] + red[4] + red[6];
    const float tq = red[1] + red[3] + red[5] + red[7];
    const float mu  = ts * (1.0f / D);
    const float var = tq * (1.0f / D) - mu * mu;
    const float inv = rsqrtf(var + LN_EPS);

    ((float*)hn4)[t] = (e - mu) * inv * lnw[t] + lnb[t];
    __syncthreads();

    // output logit u = t : dot(hn, Wout[u,:]) + bout[u], vectorized float4
    const fv4* __restrict__ w4 = (const fv4*)(Wout + t * D);
    fv4 acc = {0.f, 0.f, 0.f, 0.f};
    #pragma unroll 8
    for (int d4 = 0; d4 < D / 4; ++d4) {
        const fv4 h = hn4[d4];   // LDS broadcast (same addr all lanes)
        const fv4 w = w4[d4];
        acc += h * w;
    }
    T[v * V + t] = bout[t] + ((acc.x + acc.y) + (acc.z + acc.w));
}

// Kernel 2: out[token, :] = T[x[token], :], float4-vectorized.
// 64 consecutive float4 = one token row -> each aligned wave handles exactly
// one token per iteration (wave-uniform x, coalesced T read, streamed write).
__global__ __launch_bounds__(256) void gather_logits(
    const int* __restrict__ x,        // [B*L] token ids
    const fv4* __restrict__ T4,       // [V * (V/4)]
    fv4* __restrict__ out4,           // [B*L * (V/4)]
    int total4)
{
    int i = blockIdx.x * blockDim.x + threadIdx.x;
    const int stride = gridDim.x * blockDim.x;
    for (; i < total4; i += stride) {
        const int tok = x[i >> 6];                 // V/4 = 64 float4 per row
        const fv4 val = T4[(tok << 6) | (i & 63)];
        __builtin_nontemporal_store(val, &out4[i]);  // don't churn L2
    }
}

extern "C" void kernel_launch(void* const* d_in, const int* in_sizes, int n_in,
                              void* d_out, int out_size, void* d_ws, size_t ws_size,
                              hipStream_t stream) {
    const int*   x     = (const int*)  d_in[0];   // [B*L] = 65536
    const float* embed = (const float*)d_in[1];   // [256,256]
    const float* filt  = (const float*)d_in[2];   // [256]
    const float* lnw   = (const float*)d_in[3];
    const float* lnb   = (const float*)d_in[4];
    const float* Wout  = (const float*)d_in[5];   // [256,256]
    const float* bout  = (const float*)d_in[6];   // [256]
    float* out = (float*)d_out;

    float* T = (float*)d_ws;                      // 256*256*4 = 256 KB scratch

    build_table<<<V, 256, 0, stream>>>(embed, filt, lnw, lnb, Wout, bout, T);

    const int n_tok  = in_sizes[0];               // 65536
    const int total4 = n_tok * (V / 4);           // 4,194,304 float4
    gather_logits<<<2048, 256, 0, stream>>>(x, (const fv4*)T, (fv4*)out, total4);
}